// Round 1
// baseline (255.373 us; speedup 1.0000x reference)
//
#include <hip/hip_runtime.h>

// ---------------- problem constants ----------------
#define TDIM 48
#define DDIM 32
#define KDIM 1536      // T*D
#define HDIM 1024
#define GHID 128
#define KTN  48        // K tiles of 32 (KDIM/32)

typedef unsigned short u16;
typedef __bf16 bf16x8 __attribute__((ext_vector_type(8)));
typedef float  f32x4  __attribute__((ext_vector_type(4)));

typedef const void __attribute__((address_space(1))) gvoid;
typedef void       __attribute__((address_space(3))) lvoid;

__device__ __forceinline__ void gld_lds16(const void* g, void* l) {
    __builtin_amdgcn_global_load_lds((gvoid*)g, (lvoid*)l, 16, 0, 0);
}

__device__ __forceinline__ u16 f2bf(float f) {
    union { float f; unsigned u; } v; v.f = f;
    return (u16)((v.u + 0x7fffu + ((v.u >> 16) & 1u)) >> 16);
}

// ---------------- gate (blocks 0..Bn/4) + W1 transpose (rest) ---------------
// gate: fp64 MLP + bf16 cast of x; 4 waves/block, one sample per wave.
// Also zero-inits out[0..2B) and cnt. x single-use -> nontemporal loads.
// transpose: [1536,1024] f32 -> [1024,1536] bf16; independent of gate, so it
// overlaps with the gate's memory-bound phase inside one launch.
__global__ __launch_bounds__(256) void gate_transpose(
    const float* __restrict__ x,
    const float* __restrict__ gW1, const float* __restrict__ gb1,
    const float* __restrict__ gW2, const float* __restrict__ gb2,
    u16* __restrict__ Xbf, int* __restrict__ route, int* __restrict__ cnt,
    float* __restrict__ out, float* __restrict__ outDec, float* __restrict__ outProb,
    const float* __restrict__ nW1, const float* __restrict__ aW1,
    u16* __restrict__ W1t, int gateBlocks)
{
    __shared__ double xm[4][DDIM];
    __shared__ float tile[32][33];

    if ((int)blockIdx.x < gateBlocks) {
        const int wave = threadIdx.x >> 6;
        const int lane = threadIdx.x & 63;
        const int b    = blockIdx.x * 4 + wave;
        if (blockIdx.x == 0 && threadIdx.x < 2) cnt[threadIdx.x] = 0;

        const float* xr = x + (size_t)b * KDIM;
        u16* xo = Xbf + (size_t)b * KDIM;

        double a0 = 0, a1 = 0, a2 = 0, a3 = 0;
#pragma unroll
        for (int i = 0; i < 6; ++i) {
            const int idx = i * 256 + lane * 4;
            f32x4 v = __builtin_nontemporal_load((const f32x4*)(xr + idx));
            ushort4 o;
            o.x = f2bf(v[0]); o.y = f2bf(v[1]); o.z = f2bf(v[2]); o.w = f2bf(v[3]);
            *(ushort4*)(xo + idx) = o;
            a0 += v[0]; a1 += v[1]; a2 += v[2]; a3 += v[3];
        }
        // lanes {l, l+8, ...} share columns 4*(l&7)..+3 -> reduce over bits 3,4,5
#pragma unroll
        for (int m = 8; m <= 32; m <<= 1) {
            a0 += __shfl_xor(a0, m); a1 += __shfl_xor(a1, m);
            a2 += __shfl_xor(a2, m); a3 += __shfl_xor(a3, m);
        }
        if (lane < 8) {
            xm[wave][4 * lane + 0] = a0 / 48.0; xm[wave][4 * lane + 1] = a1 / 48.0;
            xm[wave][4 * lane + 2] = a2 / 48.0; xm[wave][4 * lane + 3] = a3 / 48.0;
        }
        __builtin_amdgcn_wave_barrier();
        __builtin_amdgcn_s_waitcnt(0);   // lgkmcnt(0): LDS writes visible within wave
        __threadfence_block();

        // hidden: lane handles j = lane and lane+64
        double h0 = (double)gb1[lane], h1 = (double)gb1[lane + 64];
#pragma unroll
        for (int d = 0; d < DDIM; ++d) {
            const double xv = xm[wave][d];
            h0 += xv * (double)gW1[d * GHID + lane];
            h1 += xv * (double)gW1[d * GHID + 64 + lane];
        }
        h0 = h0 > 0.0 ? h0 : 0.0;
        h1 = h1 > 0.0 ? h1 : 0.0;
        double z0 = h0 * (double)gW2[lane * 2 + 0] + h1 * (double)gW2[(lane + 64) * 2 + 0];
        double z1 = h0 * (double)gW2[lane * 2 + 1] + h1 * (double)gW2[(lane + 64) * 2 + 1];
#pragma unroll
        for (int m = 1; m <= 32; m <<= 1) {
            z0 += __shfl_xor(z0, m);
            z1 += __shfl_xor(z1, m);
        }
        if (lane == 0) {
            z0 += (double)gb2[0]; z1 += (double)gb2[1];
            const int dec = (z1 > z0) ? 1 : 0;      // argmax, ties -> 0
            const double mz = z0 > z1 ? z0 : z1;
            const double e0 = exp(z0 - mz), e1 = exp(z1 - mz);
            const double p = (e0 > e1 ? e0 : e1) / (e0 + e1);
            const float pf = (float)p;               // stored prob is f32
            outDec[b]  = (float)dec;
            outProb[b] = pf;
            out[2 * b + 0] = 0.f;                    // zero-init for gemm atomics
            out[2 * b + 1] = 0.f;
            const int high = ((double)pf >= 0.7) ? 1 : 0;
            route[b] = (high && dec) ? 1 : 0;
        }
    } else {
        // ---- transpose-cast ----
        int t = (int)blockIdx.x - gateBlocks;    // 0..3071
        const int e = t >= (32 * 48);
        t -= e ? (32 * 48) : 0;
        const int bx = t & 31;                  // n-tile (1024/32)
        const int by = t >> 5;                  // k-tile (1536/32)
        const float* W = e ? aW1 : nW1;
        u16* Wt = W1t + (size_t)e * HDIM * KDIM;
        const int tid = threadIdx.x;
        const int tx = tid & 31;                // 0..31
        const int ty = tid >> 5;                // 0..7
#pragma unroll
        for (int r = 0; r < 32; r += 8)
            tile[ty + r][tx] = W[(size_t)(by * 32 + ty + r) * HDIM + bx * 32 + tx];
        __syncthreads();
#pragma unroll
        for (int r = 0; r < 32; r += 8)
            Wt[(size_t)(bx * 32 + ty + r) * KDIM + by * 32 + tx] = f2bf(tile[tx][ty + r]);
    }
}

// ---------------- compaction: per-expert index lists from route[] -----------
__global__ __launch_bounds__(256) void compact_kernel(
    const int* __restrict__ route, int* __restrict__ perm, int* __restrict__ cnt,
    int Bn)
{
    const int tid  = threadIdx.x;
    const int b    = (int)blockIdx.x * 256 + tid;
    const int lane = tid & 63;
    const int active = (b < Bn);
    const int e = active ? route[b] : 0;
    const unsigned long long m1 = __ballot(active && e == 1);
    const unsigned long long m0 = __ballot(active && e == 0);
    const unsigned long long below = (lane == 63) ? ~0ull >> 1 : ((1ull << lane) - 1);
    int base0 = 0, base1 = 0;
    if (lane == 0) {
        if (m0) base0 = atomicAdd(&cnt[0], (int)__popcll(m0));
        if (m1) base1 = atomicAdd(&cnt[1], (int)__popcll(m1));
    }
    base0 = __shfl(base0, 0);
    base1 = __shfl(base1, 0);
    if (active) {
        const int pos = e ? base1 + (int)__popcll(m1 & below)
                          : base0 + (int)__popcll(m0 & below);
        perm[e * Bn + pos] = b;
    }
}

// ---------------- expert GEMM: 256x128 tile, BK=32, quad-buffered -----------
// 8 waves (4M x 2N), 16x16x32 bf16 MFMA, 16 MFMA per wave per K-tile.
// Pipeline: prefetch 3 K-tiles ahead into LDS buffer (kt+3)&3 via
// global_load_lds; counted s_waitcnt vmcnt(6) at tile end (never 0 in steady
// state) keeps 2 tiles of loads in flight across barriers.  Race-free by
// construction: writes target buffer (kt+3)&3 which is disjoint from the
// buffers read at kt..kt+2; buffer (kt+1)&3's loads are the oldest
// outstanding group, so vmcnt(6) proves them landed before the barrier.
// LDS chunk swizzle: row r (64B = 4 x 16B chunks), chunk c stored at
// position c ^ ((r>>1)&3) -> ds_read_b128 fragment reads are 2-way max (free).
// Staged via pre-swizzled per-lane GLOBAL source address (LDS dest linear,
// as global_load_lds requires).  XCD swizzle: the 8 N-siblings of an M-tile
// share blockIdx%8 so an A-tile is fetched into one XCD's L2 and reused 8x.
__global__ __launch_bounds__(512, 2) void expert_gemm(
    const u16* __restrict__ Xbf, const u16* __restrict__ W1t,
    const float* __restrict__ nb1, const float* __restrict__ nW2,
    const float* __restrict__ nb2,
    const float* __restrict__ ab1, const float* __restrict__ aW2,
    const float* __restrict__ ab2,
    const int* __restrict__ perm, const int* __restrict__ cnt,
    float* __restrict__ out, int Bn, int mB)
{
    __shared__ __align__(16) u16 Ab[4][256 * 32];   // 4 x 16 KB
    __shared__ __align__(16) u16 Bb[4][128 * 32];   // 4 x  8 KB
    __shared__ int   permLds[256];
    __shared__ float w2Lds[128 * 2];
    __shared__ float b1Lds[128];

    const int tid = threadIdx.x;
    // XCD swizzle decode: L = (m&7) + 8*((m>>3)*8 + n)  (requires mTot%8==0)
    const int L    = (int)blockIdx.x;
    const int m    = (L & 7) + 8 * (L >> 6);
    const int nIdx = (L >> 3) & 7;
    const int e  = m >= mB;
    const int mb = m - (e ? mB : 0);
    const int cntE = cnt[e];
    const int start = mb * 256;
    if (start >= cntE) return;
    const int valid = min(256, cntE - start);
    const int n0 = nIdx * 128;

    const u16*  W1e = W1t + (size_t)e * HDIM * KDIM;
    const float* b1 = e ? ab1 : nb1;
    const float* w2 = e ? aW2 : nW2;
    const float* b2 = e ? ab2 : nb2;

    if (tid < 256) {
        permLds[tid] = perm[e * Bn + min(start + tid, cntE - 1)];
    } else if (tid < 384) {
        const int j = tid - 256;
        b1Lds[j]         = b1[n0 + j];
        w2Lds[j * 2 + 0] = w2[(n0 + j) * 2 + 0];
        w2Lds[j * 2 + 1] = w2[(n0 + j) * 2 + 1];
    }
    __syncthreads();

    // staging geometry: slot s = tid (+512 for A's 2nd issue); row = s>>2,
    // pos = s&3 holds chunk cg = pos ^ ((row>>1)&3) = (tid&3) ^ ((tid>>3)&3)
    // (j-independent since rows advance by 128).
    const int rQ = tid >> 2;                          // 0..127
    const int cg = (tid & 3) ^ ((tid >> 3) & 3);
    const u16* gA0 = Xbf + (size_t)permLds[rQ]       * KDIM + cg * 8;
    const u16* gA1 = Xbf + (size_t)permLds[rQ + 128] * KDIM + cg * 8;
    const u16* gB  = W1e + (size_t)(n0 + rQ)         * KDIM + cg * 8;
    const int dA0 = tid * 8;
    const int dA1 = tid * 8 + 4096;
    const int dB  = tid * 8;

    // prologue: prefetch K-tiles 0,1,2 (3 glds each, FIFO groups)
#pragma unroll
    for (int pk = 0; pk < 3; ++pk) {
        gld_lds16(gA0 + pk * 32, &Ab[pk][dA0]);
        gld_lds16(gA1 + pk * 32, &Ab[pk][dA1]);
        gld_lds16(gB  + pk * 32, &Bb[pk][dB]);
    }
    asm volatile("s_waitcnt vmcnt(6)" ::: "memory");   // tile 0 landed
    asm volatile("s_barrier" ::: "memory");

    const int wave = tid >> 6;
    const int lane = tid & 63;
    const int wm   = (wave >> 1) * 64;     // 4 M-waves of 64 rows
    const int wn   = (wave & 1) * 64;      // 2 N-waves of 64 cols
    const int l15  = lane & 15;
    const int quad = lane >> 4;

    f32x4 acc[4][4];
#pragma unroll
    for (int i = 0; i < 4; ++i)
#pragma unroll
        for (int j = 0; j < 4; ++j) acc[i][j] = (f32x4)0.f;

#pragma unroll 4
    for (int kt = 0; kt < KTN; ++kt) {
        const int buf = kt & 3;
        bf16x8 af[4], bfv[4];
#pragma unroll
        for (int mi = 0; mi < 4; ++mi) {
            const int r = wm + mi * 16 + l15;
            const int p = quad ^ ((r >> 1) & 3);
            af[mi] = *reinterpret_cast<const bf16x8*>(&Ab[buf][r * 32 + p * 8]);
        }
#pragma unroll
        for (int ni = 0; ni < 4; ++ni) {
            const int r = wn + ni * 16 + l15;
            const int p = quad ^ ((r >> 1) & 3);
            bfv[ni] = *reinterpret_cast<const bf16x8*>(&Bb[buf][r * 32 + p * 8]);
        }
        if (kt < KTN - 3) {                 // prefetch tile kt+3 -> disjoint buffer
            const int b3 = (kt + 3) & 3;
            const int k3 = (kt + 3) * 32;
            gld_lds16(gA0 + k3, &Ab[b3][dA0]);
            gld_lds16(gA1 + k3, &Ab[b3][dA1]);
            gld_lds16(gB  + k3, &Bb[b3][dB]);
        }
        asm volatile("s_barrier" ::: "memory");
        asm volatile("s_waitcnt lgkmcnt(0)" ::: "memory");
        __builtin_amdgcn_sched_barrier(0);   // rule 18: keep MFMA below the wait
        __builtin_amdgcn_s_setprio(1);
#pragma unroll
        for (int mi = 0; mi < 4; ++mi)
#pragma unroll
            for (int ni = 0; ni < 4; ++ni)
                acc[mi][ni] = __builtin_amdgcn_mfma_f32_16x16x32_bf16(
                    af[mi], bfv[ni], acc[mi][ni], 0, 0, 0);
        __builtin_amdgcn_s_setprio(0);
        __builtin_amdgcn_sched_barrier(0);
        // counted vmcnt: oldest outstanding group = tile kt+1's 3 loads
        if (kt < KTN - 3)       { asm volatile("s_waitcnt vmcnt(6)" ::: "memory"); }
        else if (kt == KTN - 3) { asm volatile("s_waitcnt vmcnt(3)" ::: "memory"); }
        else                    { asm volatile("s_waitcnt vmcnt(0)" ::: "memory"); }
        asm volatile("s_barrier" ::: "memory");
    }

    // epilogue: h = relu(acc + b1); partial out = h @ W2[128x2]; atomic add
    const float b2_0 = (n0 == 0) ? b2[0] : 0.f;
    const float b2_1 = (n0 == 0) ? b2[1] : 0.f;
#pragma unroll
    for (int mi = 0; mi < 4; ++mi) {
        float p0[4] = {0.f, 0.f, 0.f, 0.f};
        float p1[4] = {0.f, 0.f, 0.f, 0.f};
#pragma unroll
        for (int ni = 0; ni < 4; ++ni) {
            const int col = wn + ni * 16 + l15;
            const float w20 = w2Lds[col * 2 + 0];
            const float w21 = w2Lds[col * 2 + 1];
            const float bb  = b1Lds[col];
#pragma unroll
            for (int r = 0; r < 4; ++r) {
                float h = acc[mi][ni][r] + bb;
                h = fmaxf(h, 0.f);
                p0[r] += h * w20;
                p1[r] += h * w21;
            }
        }
#pragma unroll
        for (int mm = 1; mm <= 8; mm <<= 1) {
#pragma unroll
            for (int r = 0; r < 4; ++r) {
                p0[r] += __shfl_xor(p0[r], mm);
                p1[r] += __shfl_xor(p1[r], mm);
            }
        }
        if (l15 < 4) {
            const int r = l15;
            const int lrow = wm + mi * 16 + quad * 4 + r;
            if (lrow < valid) {
                const int srow = permLds[lrow];
                atomicAdd(&out[srow * 2 + 0], p0[r] + b2_0);
                atomicAdd(&out[srow * 2 + 1], p1[r] + b2_1);
            }
        }
    }
}

// ---------------- launch ----------------
extern "C" void kernel_launch(void* const* d_in, const int* in_sizes, int n_in,
                              void* d_out, int out_size, void* d_ws, size_t ws_size,
                              hipStream_t stream) {
    const float* x   = (const float*)d_in[0];
    const float* gW1 = (const float*)d_in[1];
    const float* gb1 = (const float*)d_in[2];
    const float* gW2 = (const float*)d_in[3];
    const float* gb2 = (const float*)d_in[4];
    const float* nW1 = (const float*)d_in[5];
    const float* nb1 = (const float*)d_in[6];
    const float* nW2 = (const float*)d_in[7];
    const float* nb2 = (const float*)d_in[8];
    const float* aW1 = (const float*)d_in[9];
    const float* ab1 = (const float*)d_in[10];
    const float* aW2 = (const float*)d_in[11];
    const float* ab2 = (const float*)d_in[12];

    float* out = (float*)d_out;
    const int Bn = in_sizes[0] / KDIM;           // 16384

    // workspace layout
    char* ws = (char*)d_ws;
    size_t off = 0;
    u16* Xbf = (u16*)(ws + off); off += (size_t)Bn * KDIM * sizeof(u16);           // 50.3 MB
    u16* W1t = (u16*)(ws + off); off += (size_t)2 * HDIM * KDIM * sizeof(u16);     // 6.3 MB
    int* perm = (int*)(ws + off); off += (size_t)2 * Bn * sizeof(int);             // 128 KB
    int* cnt  = (int*)(ws + off); off += 2 * sizeof(int);
    int* route = (int*)(ws + off); off += (size_t)Bn * sizeof(int);

    const int gateBlocks = Bn / 4;               // 4096
    const int trBlocks   = 2 * (HDIM / 32) * (KDIM / 32);  // 3072

    gate_transpose<<<gateBlocks + trBlocks, 256, 0, stream>>>(
        x, gW1, gb1, gW2, gb2, Xbf, route, cnt,
        out, out + 2 * Bn, out + 3 * Bn, nW1, aW1, W1t, gateBlocks);

    compact_kernel<<<(Bn + 255) / 256, 256, 0, stream>>>(route, perm, cnt, Bn);

    const int mB = (Bn + 255) / 256;             // 64 M-tiles per expert
    expert_gemm<<<2 * mB * (HDIM / 128), 512, 0, stream>>>(
        Xbf, W1t, nb1, nW2, nb2, ab1, aW2, ab2, perm, cnt, out, Bn, mB);
}

// Round 2
// 237.706 us; speedup vs baseline: 1.0743x; 1.0743x over previous
//
#include <hip/hip_runtime.h>

// ---------------- problem constants ----------------
#define TDIM 48
#define DDIM 32
#define KDIM 1536      // T*D
#define HDIM 1024
#define GHID 128
#define KTN  48        // K tiles of 32 (KDIM/32)

typedef unsigned short u16;
typedef __bf16 bf16x8 __attribute__((ext_vector_type(8)));
typedef float  f32x4  __attribute__((ext_vector_type(4)));

typedef const void __attribute__((address_space(1))) gvoid;
typedef void       __attribute__((address_space(3))) lvoid;

__device__ __forceinline__ void gld_lds16(const void* g, void* l) {
    __builtin_amdgcn_global_load_lds((gvoid*)g, (lvoid*)l, 16, 0, 0);
}

__device__ __forceinline__ u16 f2bf(float f) {
    union { float f; unsigned u; } v; v.f = f;
    return (u16)((v.u + 0x7fffu + ((v.u >> 16) & 1u)) >> 16);
}

// ---------------- gate (blocks 0..Bn/4) + W1 transpose (rest) ---------------
// gate: fp64 MLP + bf16 cast of x; 4 waves/block, one sample per wave.
// Also zero-inits out[0..2B) and cnt. x single-use -> nontemporal loads.
// transpose: [1536,1024] f32 -> [1024,1536] bf16; independent of gate, so it
// overlaps with the gate's memory-bound phase inside one launch.
__global__ __launch_bounds__(256) void gate_transpose(
    const float* __restrict__ x,
    const float* __restrict__ gW1, const float* __restrict__ gb1,
    const float* __restrict__ gW2, const float* __restrict__ gb2,
    u16* __restrict__ Xbf, int* __restrict__ route, int* __restrict__ cnt,
    float* __restrict__ out, float* __restrict__ outDec, float* __restrict__ outProb,
    const float* __restrict__ nW1, const float* __restrict__ aW1,
    u16* __restrict__ W1t, int gateBlocks)
{
    __shared__ double xm[4][DDIM];
    __shared__ float tile[32][33];

    if ((int)blockIdx.x < gateBlocks) {
        const int wave = threadIdx.x >> 6;
        const int lane = threadIdx.x & 63;
        const int b    = blockIdx.x * 4 + wave;
        if (blockIdx.x == 0 && threadIdx.x < 2) cnt[threadIdx.x] = 0;

        const float* xr = x + (size_t)b * KDIM;
        u16* xo = Xbf + (size_t)b * KDIM;

        double a0 = 0, a1 = 0, a2 = 0, a3 = 0;
#pragma unroll
        for (int i = 0; i < 6; ++i) {
            const int idx = i * 256 + lane * 4;
            f32x4 v = __builtin_nontemporal_load((const f32x4*)(xr + idx));
            ushort4 o;
            o.x = f2bf(v[0]); o.y = f2bf(v[1]); o.z = f2bf(v[2]); o.w = f2bf(v[3]);
            *(ushort4*)(xo + idx) = o;
            a0 += v[0]; a1 += v[1]; a2 += v[2]; a3 += v[3];
        }
        // lanes {l, l+8, ...} share columns 4*(l&7)..+3 -> reduce over bits 3,4,5
#pragma unroll
        for (int m = 8; m <= 32; m <<= 1) {
            a0 += __shfl_xor(a0, m); a1 += __shfl_xor(a1, m);
            a2 += __shfl_xor(a2, m); a3 += __shfl_xor(a3, m);
        }
        if (lane < 8) {
            xm[wave][4 * lane + 0] = a0 / 48.0; xm[wave][4 * lane + 1] = a1 / 48.0;
            xm[wave][4 * lane + 2] = a2 / 48.0; xm[wave][4 * lane + 3] = a3 / 48.0;
        }
        __builtin_amdgcn_wave_barrier();
        __builtin_amdgcn_s_waitcnt(0);   // lgkmcnt(0): LDS writes visible within wave
        __threadfence_block();

        // hidden: lane handles j = lane and lane+64
        double h0 = (double)gb1[lane], h1 = (double)gb1[lane + 64];
#pragma unroll
        for (int d = 0; d < DDIM; ++d) {
            const double xv = xm[wave][d];
            h0 += xv * (double)gW1[d * GHID + lane];
            h1 += xv * (double)gW1[d * GHID + 64 + lane];
        }
        h0 = h0 > 0.0 ? h0 : 0.0;
        h1 = h1 > 0.0 ? h1 : 0.0;
        double z0 = h0 * (double)gW2[lane * 2 + 0] + h1 * (double)gW2[(lane + 64) * 2 + 0];
        double z1 = h0 * (double)gW2[lane * 2 + 1] + h1 * (double)gW2[(lane + 64) * 2 + 1];
#pragma unroll
        for (int m = 1; m <= 32; m <<= 1) {
            z0 += __shfl_xor(z0, m);
            z1 += __shfl_xor(z1, m);
        }
        if (lane == 0) {
            z0 += (double)gb2[0]; z1 += (double)gb2[1];
            const int dec = (z1 > z0) ? 1 : 0;      // argmax, ties -> 0
            const double mz = z0 > z1 ? z0 : z1;
            const double e0 = exp(z0 - mz), e1 = exp(z1 - mz);
            const double p = (e0 > e1 ? e0 : e1) / (e0 + e1);
            const float pf = (float)p;               // stored prob is f32
            outDec[b]  = (float)dec;
            outProb[b] = pf;
            out[2 * b + 0] = 0.f;                    // zero-init for gemm atomics
            out[2 * b + 1] = 0.f;
            const int high = ((double)pf >= 0.7) ? 1 : 0;
            route[b] = (high && dec) ? 1 : 0;
        }
    } else {
        // ---- transpose-cast ----
        int t = (int)blockIdx.x - gateBlocks;    // 0..3071
        const int e = t >= (32 * 48);
        t -= e ? (32 * 48) : 0;
        const int bx = t & 31;                  // n-tile (1024/32)
        const int by = t >> 5;                  // k-tile (1536/32)
        const float* W = e ? aW1 : nW1;
        u16* Wt = W1t + (size_t)e * HDIM * KDIM;
        const int tid = threadIdx.x;
        const int tx = tid & 31;                // 0..31
        const int ty = tid >> 5;                // 0..7
#pragma unroll
        for (int r = 0; r < 32; r += 8)
            tile[ty + r][tx] = W[(size_t)(by * 32 + ty + r) * HDIM + bx * 32 + tx];
        __syncthreads();
#pragma unroll
        for (int r = 0; r < 32; r += 8)
            Wt[(size_t)(bx * 32 + ty + r) * KDIM + by * 32 + tx] = f2bf(tile[tx][ty + r]);
    }
}

// ---------------- compaction: per-expert index lists from route[] -----------
__global__ __launch_bounds__(256) void compact_kernel(
    const int* __restrict__ route, int* __restrict__ perm, int* __restrict__ cnt,
    int Bn)
{
    const int tid  = threadIdx.x;
    const int b    = (int)blockIdx.x * 256 + tid;
    const int lane = tid & 63;
    const int active = (b < Bn);
    const int e = active ? route[b] : 0;
    const unsigned long long m1 = __ballot(active && e == 1);
    const unsigned long long m0 = __ballot(active && e == 0);
    const unsigned long long below = (lane == 63) ? ~0ull >> 1 : ((1ull << lane) - 1);
    int base0 = 0, base1 = 0;
    if (lane == 0) {
        if (m0) base0 = atomicAdd(&cnt[0], (int)__popcll(m0));
        if (m1) base1 = atomicAdd(&cnt[1], (int)__popcll(m1));
    }
    base0 = __shfl(base0, 0);
    base1 = __shfl(base1, 0);
    if (active) {
        const int pos = e ? base1 + (int)__popcll(m1 & below)
                          : base0 + (int)__popcll(m0 & below);
        perm[e * Bn + pos] = b;
    }
}

// ---------------- expert GEMM v3: 128x256 tile, BK=32, ring-3 LDS ----------
// 8 waves (2M x 4N), per-wave 64x64, 16x16x32 bf16 MFMA (16 MFMA/wave/K-tile).
// LDS = A 3x8KB + B 3x16KB = 72KB -> 2 blocks/CU (the round-1 regression was
// 1 block/CU + 2.03-round quantization).  Active blocks 129x4=516 on 512
// resident slots -> smooth asynchronous fill.
// Pipeline: prologue stages tiles 0..2 into slots 0..2; per K-tile kt:
//   [vmcnt(6); s_barrier; 8x ds_read_b128 frags(slot kt%3);
//    stage tile kt+2 -> slot (kt+2)%3; lgkmcnt(0); sched_barrier;
//    setprio(1); 16 MFMA; setprio(0)]
// vmcnt(6): steady outstanding = 9 (tiles kt..kt+2, 3 loads each); retiring to
// 6 proves tile kt landed.  Tail: vmcnt(3)@kt=46, vmcnt(0)@kt=47.  Stage
// target slot (kt+2)%3 was last READ at iteration kt-1; the phase-start
// barrier of kt separates those reads from the stage issue -> race-free.
// Chunk-XOR swizzle (row r: 4x16B chunks, chunk c at pos c^(r&3)), source-side
// pre-swizzle so glds dest stays linear; fragment ds_read_b128 spreads 8
// accesses/bank uniformly -> conflict-free (round-1 measured 0 conflicts).
// XCD swizzle: the 4 N-siblings of an M-tile share blockIdx%8.
__global__ __launch_bounds__(512, 4) void expert_gemm(
    const u16* __restrict__ Xbf, const u16* __restrict__ W1t,
    const float* __restrict__ nb1, const float* __restrict__ nW2,
    const float* __restrict__ nb2,
    const float* __restrict__ ab1, const float* __restrict__ aW2,
    const float* __restrict__ ab2,
    const int* __restrict__ perm, const int* __restrict__ cnt,
    float* __restrict__ out, int Bn, int mB)
{
    __shared__ __align__(16) u16 Ab[3][128 * 32];   // 3 x 8 KB
    __shared__ __align__(16) u16 Bb[3][256 * 32];   // 3 x 16 KB
    __shared__ int   permLds[128];
    __shared__ float b1Lds[256];
    __shared__ float w2Lds[256 * 2];

    const int tid = threadIdx.x;
    // XCD swizzle decode: L = ((m>>3)*4 + n)*8 + (m&7); active m spread mod 8
    const int L = (int)blockIdx.x;
    const int g = L >> 3;
    const int m = (g >> 2) * 8 + (L & 7);
    const int nIdx = g & 3;
    const int e  = m >= mB;
    const int mb = m - (e ? mB : 0);
    const int cntE = cnt[e];
    const int start = mb * 128;
    if (start >= cntE) return;
    const int valid = min(128, cntE - start);
    const int n0 = nIdx * 256;

    const u16*  W1e = W1t + (size_t)e * HDIM * KDIM;
    const float* b1 = e ? ab1 : nb1;
    const float* w2 = e ? aW2 : nW2;
    const float* b2 = e ? ab2 : nb2;

    if (tid < 128) permLds[tid] = perm[e * Bn + min(start + tid, cntE - 1)];
    if (tid >= 256) {
        const int j = tid - 256;                 // 0..255
        b1Lds[j]         = b1[n0 + j];
        w2Lds[j * 2 + 0] = w2[(n0 + j) * 2 + 0];
        w2Lds[j * 2 + 1] = w2[(n0 + j) * 2 + 1];
    }
    __syncthreads();

    // staging geometry: A tile 128x32 = 512 16B-slots (1 gld/thread);
    // B tile 256x32 = 1024 slots (2 glds/thread). slot s -> row s>>2, pos s&3;
    // pos holds global chunk cg = (s&3)^((s>>2)&3)  (j-independent for B).
    const int cg = (tid & 3) ^ ((tid >> 2) & 3);
    const int rQ = tid >> 2;                          // 0..127
    const u16* gA  = Xbf + (size_t)permLds[rQ] * KDIM + cg * 8;
    const u16* gB0 = W1e + (size_t)(n0 + rQ) * KDIM + cg * 8;
    const u16* gB1 = W1e + (size_t)(n0 + 128 + rQ) * KDIM + cg * 8;

#define STAGE(kt_, sl_) do {                                   \
        const int ko_ = (kt_) * 32;                            \
        gld_lds16(gA  + ko_, &Ab[sl_][tid * 8]);               \
        gld_lds16(gB0 + ko_, &Bb[sl_][tid * 8]);               \
        gld_lds16(gB1 + ko_, &Bb[sl_][tid * 8 + 4096]);        \
    } while (0)

    // prologue: stage tiles 0,1,2 into slots 0,1,2 (FIFO groups of 3)
    STAGE(0, 0);
    STAGE(1, 1);
    STAGE(2, 2);

    const int wave = tid >> 6;
    const int lane = tid & 63;
    const int wm   = (wave >> 2) * 64;     // 2 M-wave rows of 64
    const int wn   = (wave & 3) * 64;      // 4 N-wave cols of 64
    const int l15  = lane & 15;
    const int quad = lane >> 4;
    const int pfrag = quad ^ (l15 & 3);    // chunk pos for fragment reads

    // loop-invariant fragment LDS element offsets
    int offA[4], offB[4];
#pragma unroll
    for (int i = 0; i < 4; ++i) {
        offA[i] = (wm + i * 16 + l15) * 32 + pfrag * 8;
        offB[i] = (wn + i * 16 + l15) * 32 + pfrag * 8;
    }

    f32x4 acc[4][4];
#pragma unroll
    for (int i = 0; i < 4; ++i)
#pragma unroll
        for (int j = 0; j < 4; ++j) acc[i][j] = (f32x4)0.f;

    for (int kq = 0; kq < KTN / 3; ++kq) {
#pragma unroll
        for (int s = 0; s < 3; ++s) {
            const int kt = kq * 3 + s;
            // counted wait: prove tile kt's 3 loads landed (never 0 mid-loop)
            if (kt < KTN - 2)       { asm volatile("s_waitcnt vmcnt(6)" ::: "memory"); }
            else if (kt == KTN - 2) { asm volatile("s_waitcnt vmcnt(3)" ::: "memory"); }
            else                    { asm volatile("s_waitcnt vmcnt(0)" ::: "memory"); }
            __builtin_amdgcn_s_barrier();

            bf16x8 af[4], bfv[4];
#pragma unroll
            for (int mi = 0; mi < 4; ++mi)
                af[mi] = *reinterpret_cast<const bf16x8*>(&Ab[s][offA[mi]]);
#pragma unroll
            for (int ni = 0; ni < 4; ++ni)
                bfv[ni] = *reinterpret_cast<const bf16x8*>(&Bb[s][offB[ni]]);

            if (kt < KTN - 2) STAGE(kt + 2, (s + 2) % 3);

            asm volatile("s_waitcnt lgkmcnt(0)" ::: "memory");
            __builtin_amdgcn_sched_barrier(0);   // rule 18: MFMA stays below wait
            __builtin_amdgcn_s_setprio(1);
#pragma unroll
            for (int mi = 0; mi < 4; ++mi)
#pragma unroll
                for (int ni = 0; ni < 4; ++ni)
                    acc[mi][ni] = __builtin_amdgcn_mfma_f32_16x16x32_bf16(
                        af[mi], bfv[ni], acc[mi][ni], 0, 0, 0);
            __builtin_amdgcn_s_setprio(0);
        }
    }
#undef STAGE

    // epilogue: h = relu(acc + b1); partial out = h @ W2[256x2]; atomic add
    const float b2_0 = (n0 == 0) ? b2[0] : 0.f;
    const float b2_1 = (n0 == 0) ? b2[1] : 0.f;
#pragma unroll
    for (int mi = 0; mi < 4; ++mi) {
        float p0[4] = {0.f, 0.f, 0.f, 0.f};
        float p1[4] = {0.f, 0.f, 0.f, 0.f};
#pragma unroll
        for (int ni = 0; ni < 4; ++ni) {
            const int col = wn + ni * 16 + l15;
            const float w20 = w2Lds[col * 2 + 0];
            const float w21 = w2Lds[col * 2 + 1];
            const float bb  = b1Lds[col];
#pragma unroll
            for (int r = 0; r < 4; ++r) {
                float h = acc[mi][ni][r] + bb;
                h = fmaxf(h, 0.f);
                p0[r] += h * w20;
                p1[r] += h * w21;
            }
        }
#pragma unroll
        for (int mm = 1; mm <= 8; mm <<= 1) {
#pragma unroll
            for (int r = 0; r < 4; ++r) {
                p0[r] += __shfl_xor(p0[r], mm);
                p1[r] += __shfl_xor(p1[r], mm);
            }
        }
        if (l15 < 4) {
            const int r = l15;
            const int lrow = wm + mi * 16 + quad * 4 + r;
            if (lrow < valid) {
                const int srow = permLds[lrow];
                atomicAdd(&out[srow * 2 + 0], p0[r] + b2_0);
                atomicAdd(&out[srow * 2 + 1], p1[r] + b2_1);
            }
        }
    }
}

// ---------------- launch ----------------
extern "C" void kernel_launch(void* const* d_in, const int* in_sizes, int n_in,
                              void* d_out, int out_size, void* d_ws, size_t ws_size,
                              hipStream_t stream) {
    const float* x   = (const float*)d_in[0];
    const float* gW1 = (const float*)d_in[1];
    const float* gb1 = (const float*)d_in[2];
    const float* gW2 = (const float*)d_in[3];
    const float* gb2 = (const float*)d_in[4];
    const float* nW1 = (const float*)d_in[5];
    const float* nb1 = (const float*)d_in[6];
    const float* nW2 = (const float*)d_in[7];
    const float* nb2 = (const float*)d_in[8];
    const float* aW1 = (const float*)d_in[9];
    const float* ab1 = (const float*)d_in[10];
    const float* aW2 = (const float*)d_in[11];
    const float* ab2 = (const float*)d_in[12];

    float* out = (float*)d_out;
    const int Bn = in_sizes[0] / KDIM;           // 16384

    // workspace layout
    char* ws = (char*)d_ws;
    size_t off = 0;
    u16* Xbf = (u16*)(ws + off); off += (size_t)Bn * KDIM * sizeof(u16);           // 50.3 MB
    u16* W1t = (u16*)(ws + off); off += (size_t)2 * HDIM * KDIM * sizeof(u16);     // 6.3 MB
    int* perm = (int*)(ws + off); off += (size_t)2 * Bn * sizeof(int);             // 128 KB
    int* cnt  = (int*)(ws + off); off += 2 * sizeof(int);
    int* route = (int*)(ws + off); off += (size_t)Bn * sizeof(int);

    const int gateBlocks = Bn / 4;               // 4096
    const int trBlocks   = 2 * (HDIM / 32) * (KDIM / 32);  // 3072

    gate_transpose<<<gateBlocks + trBlocks, 256, 0, stream>>>(
        x, gW1, gb1, gW2, gb2, Xbf, route, cnt,
        out, out + 2 * Bn, out + 3 * Bn, nW1, aW1, W1t, gateBlocks);

    compact_kernel<<<(Bn + 255) / 256, 256, 0, stream>>>(route, perm, cnt, Bn);

    const int mB = (Bn + 127) / 128;             // 128 M-tiles per expert
    expert_gemm<<<2 * mB * (HDIM / 256), 512, 0, stream>>>(
        Xbf, W1t, nb1, nW2, nb2, ab1, aW2, ab2, perm, cnt, out, Bn, mB);
}